// Round 6
// baseline (153.860 us; speedup 1.0000x reference)
//
#include <hip/hip_runtime.h>

// Flash attention forward, fp32 in/out, fp16 MFMA compute.
// B=8, SQ=SK=4096, D=64. scores = (Q/x5) K^T ; softmax ; O = P V.
// R6: split-K x2 + MT=2. R5 counters: LDS data path ~89% busy; all 4 waves
// read IDENTICAL kf/vf fragments (work per LDS byte set by 16 Q-rows/wave).
// Fix: each wave owns 32 Q rows (2 M-tiles) -> kf/vf amortized over 2x MFMA.
// BQ=128 would drop grid to 256 (1 block/CU, known latency-bound) -> split
// keys into 2 halves (flash-decoding): grid = 32 x 8 x 2 = 512 blocks, still
// 2 blocks/CU. Partials (unnormalized O, m, l) in d_ws; combine kernel merges.

typedef _Float16 f16x8 __attribute__((ext_vector_type(8)));
typedef _Float16 f16x4 __attribute__((ext_vector_type(4)));
typedef __fp16   h16x2 __attribute__((ext_vector_type(2)));   // cvt_pkrtz return type
typedef float    f32x4 __attribute__((ext_vector_type(4)));

constexpr int kB  = 8;
constexpr int kSQ = 4096;
constexpr int kSK = 4096;
constexpr int kD  = 64;
constexpr int KSPLIT = 2;
constexpr int SKH = kSK / KSPLIT;   // 2048 keys per split
constexpr int BQ  = 128;            // Q rows per block (4 waves x 32 rows)
constexpr int BK  = 64;             // keys per iteration
constexpr int LDK = kD + 8;         // 72
constexpr int LDV = BK + 8;         // 72
constexpr int LDP = BK + 8;         // 72
constexpr size_t APART = (size_t)kB * kSQ * kD;   // floats per split's O-partial

static __device__ __forceinline__ f16x4 pack4(float a, float b, float c, float d) {
    h16x2 p0 = __builtin_amdgcn_cvt_pkrtz(a, b);
    h16x2 p1 = __builtin_amdgcn_cvt_pkrtz(c, d);
    f16x4 r;
    r[0] = (_Float16)p0[0]; r[1] = (_Float16)p0[1];
    r[2] = (_Float16)p1[0]; r[3] = (_Float16)p1[1];
    return r;
}

__global__ __launch_bounds__(256, 2)
void fattn_partial(const float* __restrict__ Qg,
                   const float* __restrict__ Kg,
                   const float* __restrict__ Vg,
                   const float* __restrict__ sdiv,
                   float* __restrict__ Ap,      // [KSPLIT][B][SQ][D] unnormalized
                   float2* __restrict__ MLp)    // [KSPLIT][B][SQ] (m, l)
{
    __shared__ __align__(16) _Float16 sK[2][BK][LDK];      // [buf][key][feat]
    __shared__ __align__(16) _Float16 sV[2][kD][LDV];      // [buf][feat][key swz]
    __shared__ __align__(16) _Float16 sP[4][2][16][LDP];   // [wave][mt][qrow][key]

    const int tid  = threadIdx.x;
    const int w    = tid >> 6;
    const int lane = tid & 63;
    const int l16  = lane & 15;
    const int quad = lane >> 4;

    const int b  = blockIdx.y;
    const int qb = blockIdx.x * BQ;
    const int ks = blockIdx.z;

    const float inv_scale = 1.0f / sdiv[0];

    const float* Qb = Qg + ((size_t)b * kSQ + qb) * kD;
    const float* Kb = Kg + ((size_t)b * kSK + (size_t)ks * SKH) * kD;
    const float* Vb = Vg + ((size_t)b * kSK + (size_t)ks * SKH) * kD;

    // ---- Q fragments: 2 M-tiles per wave; rows w*32 + mt*16 + l16 ----
    f16x8 qf[2][2];
#pragma unroll
    for (int mt = 0; mt < 2; ++mt) {
        const float* qrow = Qb + (size_t)(w * 32 + mt * 16 + l16) * kD;
#pragma unroll
        for (int kk = 0; kk < 2; ++kk) {
            const float4 a = *(const float4*)(qrow + kk * 32 + quad * 8);
            const float4 c = *(const float4*)(qrow + kk * 32 + quad * 8 + 4);
            f16x4 lo = pack4(a.x * inv_scale, a.y * inv_scale, a.z * inv_scale, a.w * inv_scale);
            f16x4 hi = pack4(c.x * inv_scale, c.y * inv_scale, c.z * inv_scale, c.w * inv_scale);
            f16x8 f;
            f[0] = lo[0]; f[1] = lo[1]; f[2] = lo[2]; f[3] = lo[3];
            f[4] = hi[0]; f[5] = hi[1]; f[6] = hi[2]; f[7] = hi[3];
            qf[mt][kk] = f;
        }
    }

    // ---- staging maps (same as R5) ----
    const int kp0 = 2 * ((0 * 256 + tid) >> 4), cb0 = ((0 * 256 + tid) & 15) * 4;
    const int kp1 = 2 * ((1 * 256 + tid) >> 4), cb1 = ((1 * 256 + tid) & 15) * 4;
    const int kq  = tid >> 4;
    const int fq  = tid & 15;
    const int kqs = (kq ^ (fq & 14)) * 4;

    float4 rk[2][2];
    float4 rv[4];

    auto load_tile = [&](int kt) {
        const float* Kt = Kb + (size_t)kt * BK * kD;
        const float* Vt = Vb + (size_t)kt * BK * kD;
        rk[0][0] = *(const float4*)(Kt + (kp0 + 0) * kD + cb0);
        rk[0][1] = *(const float4*)(Kt + (kp0 + 1) * kD + cb0);
        rk[1][0] = *(const float4*)(Kt + (kp1 + 0) * kD + cb1);
        rk[1][1] = *(const float4*)(Kt + (kp1 + 1) * kD + cb1);
#pragma unroll
        for (int r = 0; r < 4; ++r)
            rv[r] = *(const float4*)(Vt + (4 * kq + r) * kD + 4 * fq);
    };

    auto write_tile = [&](int buf) {
        *(f16x4*)&sK[buf][kp0 + 0][cb0] = pack4(rk[0][0].x, rk[0][0].y, rk[0][0].z, rk[0][0].w);
        *(f16x4*)&sK[buf][kp0 + 1][cb0] = pack4(rk[0][1].x, rk[0][1].y, rk[0][1].z, rk[0][1].w);
        *(f16x4*)&sK[buf][kp1 + 0][cb1] = pack4(rk[1][0].x, rk[1][0].y, rk[1][0].z, rk[1][0].w);
        *(f16x4*)&sK[buf][kp1 + 1][cb1] = pack4(rk[1][1].x, rk[1][1].y, rk[1][1].z, rk[1][1].w);
        const float vx[4][4] = {
            {rv[0].x, rv[0].y, rv[0].z, rv[0].w},
            {rv[1].x, rv[1].y, rv[1].z, rv[1].w},
            {rv[2].x, rv[2].y, rv[2].z, rv[2].w},
            {rv[3].x, rv[3].y, rv[3].z, rv[3].w}};
#pragma unroll
        for (int j = 0; j < 4; ++j)
            *(f16x4*)&sV[buf][4 * fq + j][kqs] =
                pack4(vx[0][j], vx[1][j], vx[2][j], vx[3][j]);
    };

    // ---- online-softmax state per M-tile ----
    f32x4 o[2][4];
    float m_i[2] = {-1e30f, -1e30f}, l_i[2] = {0.0f, 0.0f};
#pragma unroll
    for (int mt = 0; mt < 2; ++mt)
#pragma unroll
        for (int dt = 0; dt < 4; ++dt)
#pragma unroll
            for (int r = 0; r < 4; ++r) o[mt][dt][r] = 0.0f;

    load_tile(0);
    write_tile(0);
    __syncthreads();

    const int nIter = SKH / BK;   // 32
    for (int kt = 0; kt < nIter; ++kt) {
        const int buf = kt & 1;
        const bool more = (kt + 1 < nIter);
        if (more) load_tile(kt + 1);

        // ---- S^T = K Q^T, both M-tiles share kf reads ----
        f32x4 s[2][4];
#pragma unroll
        for (int nt = 0; nt < 4; ++nt) {
            const f16x8 kf0 = *(const f16x8*)&sK[buf][nt * 16 + l16][quad * 8];
            const f16x8 kf1 = *(const f16x8*)&sK[buf][nt * 16 + l16][32 + quad * 8];
#pragma unroll
            for (int mt = 0; mt < 2; ++mt) {
                f32x4 acc;
#pragma unroll
                for (int r = 0; r < 4; ++r) acc[r] = 0.0f;
                acc = __builtin_amdgcn_mfma_f32_16x16x32_f16(kf0, qf[mt][0], acc, 0, 0, 0);
                acc = __builtin_amdgcn_mfma_f32_16x16x32_f16(kf1, qf[mt][1], acc, 0, 0, 0);
                s[mt][nt] = acc;
            }
        }

        // ---- online softmax per M-tile (lane owns 16 keys of Q-row l16) ----
#pragma unroll
        for (int mt = 0; mt < 2; ++mt) {
            float rm = s[mt][0][0];
#pragma unroll
            for (int nt = 0; nt < 4; ++nt)
#pragma unroll
                for (int r = 0; r < 4; ++r) rm = fmaxf(rm, s[mt][nt][r]);
            rm = fmaxf(rm, __shfl_xor(rm, 16, 64));
            rm = fmaxf(rm, __shfl_xor(rm, 32, 64));
            const float mnew = fmaxf(m_i[mt], rm);
            const float alpha = __expf(m_i[mt] - mnew);
            m_i[mt] = mnew;
            float rs = 0.0f;
#pragma unroll
            for (int nt = 0; nt < 4; ++nt)
#pragma unroll
                for (int r = 0; r < 4; ++r) {
                    const float p = __expf(s[mt][nt][r] - mnew);
                    s[mt][nt][r] = p;
                    rs += p;
                }
            rs += __shfl_xor(rs, 16, 64);
            rs += __shfl_xor(rs, 32, 64);
            l_i[mt] = l_i[mt] * alpha + rs;
#pragma unroll
            for (int dt = 0; dt < 4; ++dt)
#pragma unroll
                for (int r = 0; r < 4; ++r) o[mt][dt][r] *= alpha;
#pragma unroll
            for (int nt = 0; nt < 4; ++nt)
                *(f16x4*)&sP[w][mt][l16][nt * 16 + quad * 4] =
                    pack4(s[mt][nt][0], s[mt][nt][1], s[mt][nt][2], s[mt][nt][3]);
        }

        // ---- O^T += V^T P^T, both M-tiles share vf reads ----
        const f16x8 pfa0 = *(const f16x8*)&sP[w][0][l16][quad * 8];
        const f16x8 pfa1 = *(const f16x8*)&sP[w][0][l16][32 + quad * 8];
        const f16x8 pfb0 = *(const f16x8*)&sP[w][1][l16][quad * 8];
        const f16x8 pfb1 = *(const f16x8*)&sP[w][1][l16][32 + quad * 8];
#pragma unroll
        for (int dt = 0; dt < 4; ++dt) {
            const int f  = dt * 16 + l16;
            const int sw = (f >> 2) & 14;
            const f16x8 vf0 = *(const f16x8*)&sV[buf][f][((2 * quad) ^ sw) * 4];
            const f16x8 vf1 = *(const f16x8*)&sV[buf][f][((8 + 2 * quad) ^ sw) * 4];
            o[0][dt] = __builtin_amdgcn_mfma_f32_16x16x32_f16(vf0, pfa0, o[0][dt], 0, 0, 0);
            o[0][dt] = __builtin_amdgcn_mfma_f32_16x16x32_f16(vf1, pfa1, o[0][dt], 0, 0, 0);
            o[1][dt] = __builtin_amdgcn_mfma_f32_16x16x32_f16(vf0, pfb0, o[1][dt], 0, 0, 0);
            o[1][dt] = __builtin_amdgcn_mfma_f32_16x16x32_f16(vf1, pfb1, o[1][dt], 0, 0, 0);
        }

        if (more) write_tile(buf ^ 1);
        __syncthreads();
    }

    // ---- epilogue: write unnormalized partial O + (m, l) ----
    float* Ab = Ap + (size_t)ks * APART + ((size_t)b * kSQ + qb) * kD;
    float2* MLb = MLp + (size_t)ks * kB * kSQ + (size_t)b * kSQ + qb;
#pragma unroll
    for (int mt = 0; mt < 2; ++mt) {
        const int row = w * 32 + mt * 16 + l16;
#pragma unroll
        for (int dt = 0; dt < 4; ++dt) {
            float4 st4;
            st4.x = o[mt][dt][0];
            st4.y = o[mt][dt][1];
            st4.z = o[mt][dt][2];
            st4.w = o[mt][dt][3];
            *(float4*)&Ab[(size_t)row * kD + dt * 16 + quad * 4] = st4;
        }
        if (quad == 0) MLb[row] = make_float2(m_i[mt], l_i[mt]);
    }
}

__global__ __launch_bounds__(256)
void fattn_combine(const float* __restrict__ Ap,
                   const float2* __restrict__ MLp,
                   float* __restrict__ Og)
{
    const int idx = blockIdx.x * 256 + threadIdx.x;   // [0, 524288)
    const int r = idx >> 4;                           // global row [0, 32768)
    const int c = (idx & 15) * 4;                     // feat base

    const float2 ml0 = MLp[r];
    const float2 ml1 = MLp[kB * kSQ + r];
    const float m = fmaxf(ml0.x, ml1.x);
    const float e0 = __expf(ml0.x - m);
    const float e1 = __expf(ml1.x - m);
    const float inv = 1.0f / (e0 * ml0.y + e1 * ml1.y);

    const float4 a0 = *(const float4*)&Ap[(size_t)r * kD + c];
    const float4 a1 = *(const float4*)&Ap[APART + (size_t)r * kD + c];
    float4 res;
    res.x = (e0 * a0.x + e1 * a1.x) * inv;
    res.y = (e0 * a0.y + e1 * a1.y) * inv;
    res.z = (e0 * a0.z + e1 * a1.z) * inv;
    res.w = (e0 * a0.w + e1 * a1.w) * inv;
    *(float4*)&Og[(size_t)r * kD + c] = res;
}

extern "C" void kernel_launch(void* const* d_in, const int* in_sizes, int n_in,
                              void* d_out, int out_size, void* d_ws, size_t ws_size,
                              hipStream_t stream) {
    const float* Q    = (const float*)d_in[0];
    const float* K    = (const float*)d_in[1];
    const float* V    = (const float*)d_in[2];
    // d_in[3] = dropout p (static 0) -> unused
    const float* sdiv = (const float*)d_in[4];
    float* O = (float*)d_out;

    float*  Ap  = (float*)d_ws;                       // KSPLIT * 8*4096*64 floats
    float2* MLp = (float2*)(Ap + KSPLIT * APART);     // KSPLIT * 8*4096 float2

    dim3 grid(kSQ / BQ, kB, KSPLIT);
    fattn_partial<<<grid, dim3(256), 0, stream>>>(Q, K, V, sdiv, Ap, MLp);
    fattn_combine<<<dim3(kB * kSQ * kD / (256 * 4)), dim3(256), 0, stream>>>(Ap, MLp, O);
}

// Round 7
// 146.658 us; speedup vs baseline: 1.0491x; 1.0491x over previous
//
#include <hip/hip_runtime.h>

// Flash attention forward, fp32 in/out, fp16 MFMA compute.
// B=8, SQ=SK=4096, D=64. scores = (Q/x5) K^T ; softmax ; O = P V.
// R7: kill the staging pipeline. Pre-pass converts K -> fp16 (feat-block
// xor-swizzle) and V -> V^T fp16 (key-block xor-swizzle, 64-key tiles) in
// d_ws; main kernel stages tiles with global_load_lds width=16 (4 instr/wave
// replaces 8 float4 loads + ~40 VALU + 8 ds_writes). Unpadded LDS, swizzle
// makes b128 fragment reads conflict-free. LDS 50 KB -> 3 blocks/CU;
// KSPLIT=4 (grid 1024) supplies residency. Partials fp16.

typedef _Float16 f16x8 __attribute__((ext_vector_type(8)));
typedef _Float16 f16x4 __attribute__((ext_vector_type(4)));
typedef __fp16   h16x2 __attribute__((ext_vector_type(2)));
typedef float    f32x4 __attribute__((ext_vector_type(4)));

constexpr int kB  = 8;
constexpr int kSQ = 4096;
constexpr int kSK = 4096;
constexpr int kD  = 64;
constexpr int KSPLIT = 4;
constexpr int SKH = kSK / KSPLIT;     // 1024 keys per split
constexpr int BQ  = 128;              // 4 waves x 32 Q rows
constexpr int BK  = 64;
constexpr int LDP = BK + 8;           // sP padding (VALU-written)
constexpr size_t APART = (size_t)kB * kSQ * kD;   // elements per split partial

static __device__ __forceinline__ f16x4 pack4(float a, float b, float c, float d) {
    h16x2 p0 = __builtin_amdgcn_cvt_pkrtz(a, b);
    h16x2 p1 = __builtin_amdgcn_cvt_pkrtz(c, d);
    f16x4 r;
    r[0] = (_Float16)p0[0]; r[1] = (_Float16)p0[1];
    r[2] = (_Float16)p1[0]; r[3] = (_Float16)p1[1];
    return r;
}
static __device__ __forceinline__ f16x8 pack8(const float4& a, const float4& c) {
    f16x4 lo = pack4(a.x, a.y, a.z, a.w);
    f16x4 hi = pack4(c.x, c.y, c.z, c.w);
    f16x8 f;
    f[0] = lo[0]; f[1] = lo[1]; f[2] = lo[2]; f[3] = lo[3];
    f[4] = hi[0]; f[5] = hi[1]; f[6] = hi[2]; f[7] = hi[3];
    return f;
}

typedef const __attribute__((address_space(1))) unsigned int* gu32p;
typedef __attribute__((address_space(3))) unsigned int* lu32p;
static __device__ __forceinline__ void gload_lds16(const void* g, void* l) {
    __builtin_amdgcn_global_load_lds((gu32p)g, (lu32p)l, 16, 0, 0);
}

// ---------------- pre-pass: K -> Kh (swizzled fp16), V -> Vt (transposed,
// tiled, swizzled fp16). Kh[b][k][blk fb^(k&7)][8]; Vt[b][kt][f][blk kb^(f&7)][8].
__global__ __launch_bounds__(256, 2)
void fattn_prepass(const float* __restrict__ Kg,
                   const float* __restrict__ Vg,
                   _Float16* __restrict__ Kh,
                   _Float16* __restrict__ Vt)
{
    __shared__ _Float16 tr[kD][BK];    // [feat][key] transpose buffer

    const int tid = threadIdx.x;
    const int kt  = blockIdx.x;        // key-tile 0..63
    const int b   = blockIdx.y;

    const int k = tid >> 2;            // 0..63 key within tile
    const int p = tid & 3;             // feat quarter (16 feats)
    const int gk = kt * BK + k;

    // ---- K: row-wise convert + feat-block swizzle ----
    {
        const float* src = Kg + ((size_t)b * kSK + gk) * kD + p * 16;
        const float4 a0 = *(const float4*)(src + 0);
        const float4 a1 = *(const float4*)(src + 4);
        const float4 a2 = *(const float4*)(src + 8);
        const float4 a3 = *(const float4*)(src + 12);
        _Float16* dst = Kh + ((size_t)b * kSK + gk) * kD;
        const int fb0 = 2 * p, fb1 = 2 * p + 1;
        *(f16x8*)&dst[(fb0 ^ (gk & 7)) * 8] = pack8(a0, a1);
        *(f16x8*)&dst[(fb1 ^ (gk & 7)) * 8] = pack8(a2, a3);
    }

    // ---- V: transpose through LDS, key-block swizzle on output ----
    {
        const float* src = Vg + ((size_t)b * kSK + gk) * kD + p * 16;
        const float4 a0 = *(const float4*)(src + 0);
        const float4 a1 = *(const float4*)(src + 4);
        const float4 a2 = *(const float4*)(src + 8);
        const float4 a3 = *(const float4*)(src + 12);
        const float v[16] = {a0.x,a0.y,a0.z,a0.w, a1.x,a1.y,a1.z,a1.w,
                             a2.x,a2.y,a2.z,a2.w, a3.x,a3.y,a3.z,a3.w};
#pragma unroll
        for (int j = 0; j < 16; ++j)
            tr[p * 16 + j][k] = (_Float16)v[j];
    }
    __syncthreads();
    {
        const int f  = tid >> 2;       // feat 0..63
        const int p2 = tid & 3;        // key quarter
        const f16x8 b0 = *(const f16x8*)&tr[f][p2 * 16 + 0];
        const f16x8 b1 = *(const f16x8*)&tr[f][p2 * 16 + 8];
        _Float16* dst = Vt + (((size_t)b * 64 + kt) * kD + f) * BK;
        const int kb0 = 2 * p2, kb1 = 2 * p2 + 1;
        *(f16x8*)&dst[(kb0 ^ (f & 7)) * 8] = b0;
        *(f16x8*)&dst[(kb1 ^ (f & 7)) * 8] = b1;
    }
}

// ---------------- main partial kernel ----------------
__global__ __launch_bounds__(256, 3)
void fattn_partial(const float* __restrict__ Qg,
                   const _Float16* __restrict__ Kh,
                   const _Float16* __restrict__ Vt,
                   const float* __restrict__ sdiv,
                   _Float16* __restrict__ Ap,   // [KSPLIT][B][SQ][D] unnormalized
                   float2* __restrict__ MLp)    // [KSPLIT][B][SQ] (m, l)
{
    __shared__ __align__(16) _Float16 sK[2][BK * kD];      // [buf][key*64 + swz-blk]
    __shared__ __align__(16) _Float16 sV[2][kD * BK];      // [buf][feat*64 + swz-blk]
    __shared__ __align__(16) _Float16 sP[4][2][16][LDP];   // [wave][mt][qrow][key]

    const int tid  = threadIdx.x;
    const int w    = tid >> 6;
    const int lane = tid & 63;
    const int l16  = lane & 15;
    const int quad = lane >> 4;
    const int sw   = (quad ^ (l16 & 7)) * 8;   // swizzled block offset (halves)

    const int b  = blockIdx.y;
    const int qb = blockIdx.x * BQ;
    const int ks = blockIdx.z;

    const float inv_scale = 1.0f / sdiv[0];

    const float* Qb = Qg + ((size_t)b * kSQ + qb) * kD;
    const _Float16* Khb = Kh + ((size_t)b * kSK + (size_t)ks * SKH) * kD;
    const _Float16* Vtb = Vt + (((size_t)b * 64 + (size_t)ks * (SKH / BK)) * kD) * BK;

    // ---- Q fragments: 2 M-tiles per wave ----
    f16x8 qf[2][2];
#pragma unroll
    for (int mt = 0; mt < 2; ++mt) {
        const float* qrow = Qb + (size_t)(w * 32 + mt * 16 + l16) * kD;
#pragma unroll
        for (int kk = 0; kk < 2; ++kk) {
            const float4 a = *(const float4*)(qrow + kk * 32 + quad * 8);
            const float4 c = *(const float4*)(qrow + kk * 32 + quad * 8 + 4);
            float4 as = make_float4(a.x * inv_scale, a.y * inv_scale, a.z * inv_scale, a.w * inv_scale);
            float4 cs = make_float4(c.x * inv_scale, c.y * inv_scale, c.z * inv_scale, c.w * inv_scale);
            qf[mt][kk] = pack8(as, cs);
        }
    }

    // ---- async staging: 4 global_load_lds per wave (2 K + 2 V chunks) ----
    auto stage = [&](int kt, int buf) {
        const char* gk = (const char*)(Khb + (size_t)kt * BK * kD) + w * 2048 + lane * 16;
        const char* gv = (const char*)(Vtb + (size_t)kt * kD * BK) + w * 2048 + lane * 16;
        char* lk = (char*)&sK[buf][0] + w * 2048;
        char* lv = (char*)&sV[buf][0] + w * 2048;
        gload_lds16(gk,        lk);
        gload_lds16(gk + 1024, lk + 1024);
        gload_lds16(gv,        lv);
        gload_lds16(gv + 1024, lv + 1024);
    };

    // ---- online-softmax state per M-tile ----
    f32x4 o[2][4];
    float m_i[2] = {-1e30f, -1e30f}, l_i[2] = {0.0f, 0.0f};
#pragma unroll
    for (int mt = 0; mt < 2; ++mt)
#pragma unroll
        for (int dt = 0; dt < 4; ++dt)
#pragma unroll
            for (int r = 0; r < 4; ++r) o[mt][dt][r] = 0.0f;

    stage(0, 0);
    __syncthreads();

    const int nIter = SKH / BK;   // 16
    for (int kt = 0; kt < nIter; ++kt) {
        const int buf = kt & 1;
        const bool more = (kt + 1 < nIter);
        if (more) stage(kt + 1, buf ^ 1);   // DMA in flight during compute

        // ---- S^T = K Q^T (kf shared across both M-tiles) ----
        f32x4 s[2][4];
#pragma unroll
        for (int nt = 0; nt < 4; ++nt) {
            const int krow = (nt * 16 + l16) * kD;
            const f16x8 kf0 = *(const f16x8*)&sK[buf][krow + sw];
            const f16x8 kf1 = *(const f16x8*)&sK[buf][krow + (sw ^ 32)];
#pragma unroll
            for (int mt = 0; mt < 2; ++mt) {
                f32x4 acc;
#pragma unroll
                for (int r = 0; r < 4; ++r) acc[r] = 0.0f;
                acc = __builtin_amdgcn_mfma_f32_16x16x32_f16(kf0, qf[mt][0], acc, 0, 0, 0);
                acc = __builtin_amdgcn_mfma_f32_16x16x32_f16(kf1, qf[mt][1], acc, 0, 0, 0);
                s[mt][nt] = acc;
            }
        }

        // ---- online softmax per M-tile ----
#pragma unroll
        for (int mt = 0; mt < 2; ++mt) {
            float rm = s[mt][0][0];
#pragma unroll
            for (int nt = 0; nt < 4; ++nt)
#pragma unroll
                for (int r = 0; r < 4; ++r) rm = fmaxf(rm, s[mt][nt][r]);
            rm = fmaxf(rm, __shfl_xor(rm, 16, 64));
            rm = fmaxf(rm, __shfl_xor(rm, 32, 64));
            const float mnew = fmaxf(m_i[mt], rm);
            const float alpha = __expf(m_i[mt] - mnew);
            m_i[mt] = mnew;
            float rs = 0.0f;
#pragma unroll
            for (int nt = 0; nt < 4; ++nt)
#pragma unroll
                for (int r = 0; r < 4; ++r) {
                    const float p = __expf(s[mt][nt][r] - mnew);
                    s[mt][nt][r] = p;
                    rs += p;
                }
            rs += __shfl_xor(rs, 16, 64);
            rs += __shfl_xor(rs, 32, 64);
            l_i[mt] = l_i[mt] * alpha + rs;
#pragma unroll
            for (int dt = 0; dt < 4; ++dt)
#pragma unroll
                for (int r = 0; r < 4; ++r) o[mt][dt][r] *= alpha;
#pragma unroll
            for (int nt = 0; nt < 4; ++nt)
                *(f16x4*)&sP[w][mt][l16][nt * 16 + quad * 4] =
                    pack4(s[mt][nt][0], s[mt][nt][1], s[mt][nt][2], s[mt][nt][3]);
        }

        // ---- O^T += V^T P^T (vf shared across both M-tiles) ----
        const f16x8 pfa0 = *(const f16x8*)&sP[w][0][l16][quad * 8];
        const f16x8 pfa1 = *(const f16x8*)&sP[w][0][l16][32 + quad * 8];
        const f16x8 pfb0 = *(const f16x8*)&sP[w][1][l16][quad * 8];
        const f16x8 pfb1 = *(const f16x8*)&sP[w][1][l16][32 + quad * 8];
#pragma unroll
        for (int dt = 0; dt < 4; ++dt) {
            const int frow = (dt * 16 + l16) * BK;
            const f16x8 vf0 = *(const f16x8*)&sV[buf][frow + sw];
            const f16x8 vf1 = *(const f16x8*)&sV[buf][frow + (sw ^ 32)];
            o[0][dt] = __builtin_amdgcn_mfma_f32_16x16x32_f16(vf0, pfa0, o[0][dt], 0, 0, 0);
            o[0][dt] = __builtin_amdgcn_mfma_f32_16x16x32_f16(vf1, pfa1, o[0][dt], 0, 0, 0);
            o[1][dt] = __builtin_amdgcn_mfma_f32_16x16x32_f16(vf0, pfb0, o[1][dt], 0, 0, 0);
            o[1][dt] = __builtin_amdgcn_mfma_f32_16x16x32_f16(vf1, pfb1, o[1][dt], 0, 0, 0);
        }

        __syncthreads();   // drains prefetch DMA (vmcnt) + LDS
    }

    // ---- epilogue: fp16 unnormalized partial + (m, l) ----
    _Float16* Ab = Ap + (size_t)ks * APART + ((size_t)b * kSQ + qb) * kD;
    float2* MLb = MLp + (size_t)ks * kB * kSQ + (size_t)b * kSQ + qb;
#pragma unroll
    for (int mt = 0; mt < 2; ++mt) {
        const int row = w * 32 + mt * 16 + l16;
#pragma unroll
        for (int dt = 0; dt < 4; ++dt)
            *(f16x4*)&Ab[(size_t)row * kD + dt * 16 + quad * 4] =
                pack4(o[mt][dt][0], o[mt][dt][1], o[mt][dt][2], o[mt][dt][3]);
        if (quad == 0) MLb[row] = make_float2(m_i[mt], l_i[mt]);
    }
}

// ---------------- combine ----------------
__global__ __launch_bounds__(256)
void fattn_combine(const _Float16* __restrict__ Ap,
                   const float2* __restrict__ MLp,
                   float* __restrict__ Og)
{
    const int idx = blockIdx.x * 256 + threadIdx.x;   // [0, 524288)
    const int r = idx >> 4;
    const int c = (idx & 15) * 4;

    float m = -1e30f;
    float2 ml[KSPLIT];
#pragma unroll
    for (int s = 0; s < KSPLIT; ++s) {
        ml[s] = MLp[(size_t)s * kB * kSQ + r];
        m = fmaxf(m, ml[s].x);
    }
    float acc[4] = {0.f, 0.f, 0.f, 0.f};
    float lsum = 0.f;
#pragma unroll
    for (int s = 0; s < KSPLIT; ++s) {
        const float e = __expf(ml[s].x - m);
        lsum += e * ml[s].y;
        const f16x4 a = *(const f16x4*)&Ap[(size_t)s * APART + (size_t)r * kD + c];
#pragma unroll
        for (int j = 0; j < 4; ++j) acc[j] += e * (float)a[j];
    }
    const float inv = 1.0f / lsum;
    float4 res = make_float4(acc[0] * inv, acc[1] * inv, acc[2] * inv, acc[3] * inv);
    *(float4*)&Og[(size_t)r * kD + c] = res;
}

extern "C" void kernel_launch(void* const* d_in, const int* in_sizes, int n_in,
                              void* d_out, int out_size, void* d_ws, size_t ws_size,
                              hipStream_t stream) {
    const float* Q    = (const float*)d_in[0];
    const float* K    = (const float*)d_in[1];
    const float* V    = (const float*)d_in[2];
    // d_in[3] = dropout p (static 0) -> unused
    const float* sdiv = (const float*)d_in[4];
    float* O = (float*)d_out;

    // workspace layout (bytes): Kh 4MB | Vt 4MB | Ap fp16 16.8MB | MLp 1MB
    _Float16* Kh  = (_Float16*)d_ws;
    _Float16* Vt  = Kh + (size_t)kB * kSK * kD;
    _Float16* Ap  = Vt + (size_t)kB * kSK * kD;
    float2*   MLp = (float2*)(Ap + (size_t)KSPLIT * APART);

    fattn_prepass<<<dim3(kSK / BK, kB), dim3(256), 0, stream>>>(K, V, Kh, Vt);
    dim3 grid(kSQ / BQ, kB, KSPLIT);
    fattn_partial<<<grid, dim3(256), 0, stream>>>(Q, Kh, Vt, sdiv, Ap, MLp);
    fattn_combine<<<dim3(kB * kSQ * kD / (256 * 4)), dim3(256), 0, stream>>>(Ap, MLp, O);
}